// Round 5
// baseline (3744.698 us; speedup 1.0000x reference)
//
#include <hip/hip_runtime.h>

// TemporalAttentionDecoder_three_step: B=512, T=64, M=P=256.
// ESTABLISHED: inputs float32 (R2 bf16-read NaN'd, R3/R4 mode-dispatch finite);
// output float32 (R3/R4 bf16-write gave absmax 0.3496 == the exact signature of
// u16-pair-packed reads: f32[i] ~ our elem 2i+1 + zeroed tail; contract says
// out dtype = reference output dtype = f32). R5 = R4 verbatim + f32 stores.
//   - dtype detect per-block (E's first 1024 u16 as bf16: f32-mantissa halves
//     give |x|>1000/NaN with certainty; true bf16 N(0,1) never does);
//     both template modes launched, non-matching exits uniformly.
//   - y1[t,n] = sum_m E[b,t,m]*Ud[n,m] computed in-kernel into LDS (bf16).
//   - scan: 256 WGs x 512 thr; each WG owns 2 batch rows (independent).
//     Per step: A: x1=[h,c]@Wd^T+b  (k-split halves, Wd row read once/CU,
//                  shared in-register across both rows)
//               B: z=tanh(x1+y1), l=z.vd, softmax_t, ct=beta.E,
//                  ytil=ct.wt+y*wt+b
//               C: g=ytil*Wih + h@Whh^T + bias; i,f,g,o gates; h,c update
//     State f32 in LDS; math f32; bf16 only y1 staging.
// LDS: y1l 64K + hs 4K + ctx 2K + x1s 2K + pg(part/gbuf overlay) 8K +
//      lpart 2K + betas .5K + misc ~= 83KB static (<160KB, 1 WG/CU).

typedef unsigned short u16;
typedef unsigned int u32;

#define BB 512
#define TT 64
#define MM 256
#define PP 256

__device__ __forceinline__ float bf2f(u16 v) {
  union { u32 u; float f; } x; x.u = ((u32)v) << 16; return x.f;
}
__device__ __forceinline__ u16 f2bf(float f) {
  union { u32 u; float f; } x; x.f = f;
  return (u16)((x.u + 0x7fffu + ((x.u >> 16) & 1u)) >> 16);
}
__device__ __forceinline__ void unpack8(uint4 v, float f[8]) {
  union { u32 u; float f; } a;
  a.u = v.x << 16;         f[0] = a.f;
  a.u = v.x & 0xffff0000u; f[1] = a.f;
  a.u = v.y << 16;         f[2] = a.f;
  a.u = v.y & 0xffff0000u; f[3] = a.f;
  a.u = v.z << 16;         f[4] = a.f;
  a.u = v.z & 0xffff0000u; f[5] = a.f;
  a.u = v.w << 16;         f[6] = a.f;
  a.u = v.w & 0xffff0000u; f[7] = a.f;
}
__device__ __forceinline__ float tanh_fast(float x) {
  // tanh(x) = 1 - 2/(1+e^{2x}); saturates correctly at both extremes
  float e = __builtin_amdgcn_exp2f(x * 2.885390081777927f);
  return 1.0f - 2.0f * __builtin_amdgcn_rcpf(1.0f + e);
}
__device__ __forceinline__ float sigmoid_fast(float x) {
  float e = __builtin_amdgcn_exp2f(x * -1.4426950408889634f);
  return __builtin_amdgcn_rcpf(1.0f + e);
}

// ---- dtype-polymorphic global IO (MODE 0 = bf16, MODE 1 = f32) ----
template <int MODE> struct GIO {
  static __device__ __forceinline__ float ld(const void* p, size_t i) {
    if (MODE == 0) return bf2f(((const u16*)p)[i]);
    return ((const float*)p)[i];
  }
  static __device__ __forceinline__ void ld8(const void* p, size_t i, float f[8]) {
    if (MODE == 0) {
      uint4 v = *(const uint4*)((const u16*)p + i);
      unpack8(v, f);
    } else {
      float4 a = *(const float4*)((const float*)p + i);
      float4 b = *(const float4*)((const float*)p + i + 4);
      f[0]=a.x; f[1]=a.y; f[2]=a.z; f[3]=a.w;
      f[4]=b.x; f[5]=b.y; f[6]=b.z; f[7]=b.w;
    }
  }
};

// part/gbuf overlay macros (disjoint, barrier-separated lifetimes)
#define PART(kh, row, n) pg[(kh) * 512 + (row) * 256 + (n)]
#define GBUF(row, n)     pg[(row) * 1024 + (n)]

template <int MODE>
__global__ __launch_bounds__(512) void scan_kernel(
    const void* __restrict__ E,      // (B,T,M)
    const void* __restrict__ yin,    // (B,T,1)
    const void* __restrict__ tar,    // (B,2)
    const int*  __restrict__ train,  // (1)
    const void* __restrict__ Wd_w,   // (256,512)
    const void* __restrict__ Wd_b,   // (256)
    const void* __restrict__ Ud_w,   // (256,256)
    const void* __restrict__ vd_w,   // (256)
    const void* __restrict__ wt_w,   // (257)
    const void* __restrict__ wt_b,   // (1)
    const void* __restrict__ Wy_w,   // (256,512)
    const void* __restrict__ Wy_b,   // (256)
    const void* __restrict__ vy_w,   // (256)
    const void* __restrict__ vy_b,   // (1)
    const void* __restrict__ Wih,    // (1024)
    const void* __restrict__ Whh,    // (1024,256)
    const void* __restrict__ bih,    // (1024)
    const void* __restrict__ bhh,    // (1024)
    float* __restrict__ out)         // (3*B) float32
{
  __shared__ __align__(16) u16   y1l[2][TT * MM];   // 64KB, bf16 y1 per row
  __shared__ __align__(16) float hs[2][2 * PP];     // [row][ h(256) | c(256) ]
  __shared__ __align__(16) float ctx[2][MM];
  __shared__ __align__(16) float x1s[2][MM];
  __shared__ __align__(16) float pg[2048];          // part / gbuf overlay
  __shared__ __align__(16) float lpart[2][4][TT];
  __shared__ __align__(16) float betas[2][TT];
  __shared__ float red[2][8];
  __shared__ float ytil_s[2];
  __shared__ float sc[2][4];   // [0]=last head value, [1]=ct.wt dot
  __shared__ int badf;

  const int tid  = threadIdx.x;
  const int half = tid >> 8;       // which of the WG's 2 batch rows
  const int j    = tid & 255;
  const int b    = blockIdx.x * 2 + half;

  // ---- in-block dtype detection (uniform result across all blocks) ----
  if (tid == 0) badf = 0;
  __syncthreads();
  {
    const u16* E16 = (const u16*)E;
    float a0 = fabsf(bf2f(E16[tid]));
    float a1 = fabsf(bf2f(E16[tid + 512]));
    if (!(a0 <= 1000.0f) || !(a1 <= 1000.0f)) atomicOr(&badf, 1); // NaN too
  }
  __syncthreads();
  if ((badf ? 1 : 0) != MODE) return;   // uniform exit

  // ---- init state ----
  for (int i = tid; i < 2 * 2 * PP; i += 512) (&hs[0][0])[i] = 0.f;
  float creg = 0.f;

  // ---- y1 into LDS: thread (half, j) computes column j for all t ----
  {
    const size_t eb = (size_t)b * TT * MM;
    const size_t uj = (size_t)j * MM;
    for (int t0 = 0; t0 < TT; t0 += 16) {
      float acc[16];
#pragma unroll
      for (int i = 0; i < 16; ++i) acc[i] = 0.f;
      for (int m0 = 0; m0 < MM; m0 += 8) {
        float w[8]; GIO<MODE>::ld8(Ud_w, uj + m0, w);
#pragma unroll
        for (int tt = 0; tt < 16; ++tt) {
          float e[8]; GIO<MODE>::ld8(E, eb + (size_t)(t0 + tt) * MM + m0, e);
#pragma unroll
          for (int mm = 0; mm < 8; ++mm) acc[tt] = fmaf(e[mm], w[mm], acc[tt]);
        }
      }
#pragma unroll
      for (int tt = 0; tt < 16; ++tt)
        y1l[half][(t0 + tt) * MM + j] = f2bf(acc[tt]);
    }
  }
  __syncthreads();

  auto lstm_step = [&]() {
    {
      const int n1 = tid, n2 = tid + 512;
      float a00 = 0.f, a01 = 0.f, a10 = 0.f, a11 = 0.f;
#pragma unroll 2
      for (int k0 = 0; k0 < PP; k0 += 8) {
        float f1[8], f2[8];
        GIO<MODE>::ld8(Whh, (size_t)n1 * PP + k0, f1);
        GIO<MODE>::ld8(Whh, (size_t)n2 * PP + k0, f2);
        float4 p0 = *(const float4*)&hs[0][k0];
        float4 p1 = *(const float4*)&hs[0][k0 + 4];
        float4 q0 = *(const float4*)&hs[1][k0];
        float4 q1 = *(const float4*)&hs[1][k0 + 4];
        float h0[8] = {p0.x,p0.y,p0.z,p0.w,p1.x,p1.y,p1.z,p1.w};
        float h1[8] = {q0.x,q0.y,q0.z,q0.w,q1.x,q1.y,q1.z,q1.w};
#pragma unroll
        for (int kk = 0; kk < 8; ++kk) {
          a00 = fmaf(h0[kk], f1[kk], a00);
          a01 = fmaf(h1[kk], f1[kk], a01);
          a10 = fmaf(h0[kk], f2[kk], a10);
          a11 = fmaf(h1[kk], f2[kk], a11);
        }
      }
      const float bs1 = GIO<MODE>::ld(bih, n1) + GIO<MODE>::ld(bhh, n1);
      const float bs2 = GIO<MODE>::ld(bih, n2) + GIO<MODE>::ld(bhh, n2);
      const float wi1 = GIO<MODE>::ld(Wih, n1);
      const float wi2 = GIO<MODE>::ld(Wih, n2);
      const float yt0 = ytil_s[0], yt1 = ytil_s[1];
      GBUF(0, n1) = a00 + yt0 * wi1 + bs1;
      GBUF(1, n1) = a01 + yt1 * wi1 + bs1;
      GBUF(0, n2) = a10 + yt0 * wi2 + bs2;
      GBUF(1, n2) = a11 + yt1 * wi2 + bs2;
    }
    __syncthreads();
    {
      // torch LSTMCell gate order i,f,g,o
      float gi = GBUF(half, j);
      float gf = GBUF(half, j + 256);
      float gg = GBUF(half, j + 512);
      float go = GBUF(half, j + 768);
      float c = sigmoid_fast(gf) * creg + sigmoid_fast(gi) * tanh_fast(gg);
      float h = sigmoid_fast(go) * tanh_fast(c);
      creg = c;
      hs[half][j]      = h;
      hs[half][PP + j] = c;
    }
    __syncthreads();
  };

  auto head_store = [&](int outIdx) {
    {
      const int n = tid & 255, kh = tid >> 8;
      const size_t wbase = (size_t)n * 512 + (size_t)kh * 256;
      const float* __restrict__ s0 = kh ? &ctx[0][0] : &hs[0][0];
      const float* __restrict__ s1 = kh ? &ctx[1][0] : &hs[1][0];
      float p0 = 0.f, p1 = 0.f;
#pragma unroll 2
      for (int k0 = 0; k0 < 256; k0 += 8) {
        float w[8]; GIO<MODE>::ld8(Wy_w, wbase + k0, w);
        float4 a0 = *(const float4*)&s0[k0];
        float4 a1 = *(const float4*)&s0[k0 + 4];
        float4 b0 = *(const float4*)&s1[k0];
        float4 b1 = *(const float4*)&s1[k0 + 4];
        float A [8] = {a0.x,a0.y,a0.z,a0.w,a1.x,a1.y,a1.z,a1.w};
        float Bv[8] = {b0.x,b0.y,b0.z,b0.w,b1.x,b1.y,b1.z,b1.w};
#pragma unroll
        for (int kk = 0; kk < 8; ++kk) {
          p0 = fmaf(A[kk],  w[kk], p0);
          p1 = fmaf(Bv[kk], w[kk], p1);
        }
      }
      PART(kh, 0, n) = p0;
      PART(kh, 1, n) = p1;
    }
    __syncthreads();
    {
      float hp = PART(0, half, j) + PART(1, half, j) + GIO<MODE>::ld(Wy_b, j);
      float pp = hp * GIO<MODE>::ld(vy_w, j);
#pragma unroll
      for (int off = 32; off; off >>= 1) pp += __shfl_xor(pp, off, 64);
      if ((j & 63) == 0) red[half][j >> 6] = pp;
    }
    __syncthreads();
    if (j == 0) {
      float o = red[half][0] + red[half][1] + red[half][2] + red[half][3]
              + GIO<MODE>::ld(vy_b, 0);
      out[(size_t)outIdx * BB + b] = o;     // f32 store (R5 fix)
      sc[half][0] = o;
    }
    __syncthreads();
  };

  // ================= scan over T steps =================
  for (int step = 0; step < TT; ++step) {
    // ---- Phase A: x1 = concat[h,c] @ Wd^T + Wd_b ----
    {
      const int n = tid & 255, kh = tid >> 8;  // k-half: kh=0->h, 1->c
      const size_t wbase = (size_t)n * 512 + (size_t)kh * 256;
      const float* __restrict__ s0 = &hs[0][kh * 256];
      const float* __restrict__ s1 = &hs[1][kh * 256];
      float p0 = 0.f, p1 = 0.f;
#pragma unroll 2
      for (int k0 = 0; k0 < 256; k0 += 8) {
        float w[8]; GIO<MODE>::ld8(Wd_w, wbase + k0, w);
        float4 a0 = *(const float4*)&s0[k0];
        float4 a1 = *(const float4*)&s0[k0 + 4];
        float4 b0 = *(const float4*)&s1[k0];
        float4 b1 = *(const float4*)&s1[k0 + 4];
        float A [8] = {a0.x,a0.y,a0.z,a0.w,a1.x,a1.y,a1.z,a1.w};
        float Bv[8] = {b0.x,b0.y,b0.z,b0.w,b1.x,b1.y,b1.z,b1.w};
#pragma unroll
        for (int kk = 0; kk < 8; ++kk) {
          p0 = fmaf(A[kk],  w[kk], p0);
          p1 = fmaf(Bv[kk], w[kk], p1);
        }
      }
      PART(kh, 0, n) = p0;
      PART(kh, 1, n) = p1;
    }
    __syncthreads();
    x1s[half][j] = PART(0, half, j) + PART(1, half, j) + GIO<MODE>::ld(Wd_b, j);
    __syncthreads();

    // ---- Phase B1: l[t] partials over m-quarters (y1 from LDS) ----
    {
      const int q = j >> 6, tq = j & 63;   // thread = (m-quarter, t)
      const u16* __restrict__ yrow = &y1l[half][tq * MM + q * 64];
      const float* __restrict__ xp = &x1s[half][q * 64];
      float lp = 0.f;
#pragma unroll 2
      for (int m0 = 0; m0 < 64; m0 += 8) {
        uint4 yv = *(const uint4*)(yrow + m0);
        float yf[8]; unpack8(yv, yf);
        float vf[8]; GIO<MODE>::ld8(vd_w, (size_t)q * 64 + m0, vf);
        float4 x0 = *(const float4*)&xp[m0];
        float4 x1 = *(const float4*)&xp[m0 + 4];
        float xf[8] = {x0.x,x0.y,x0.z,x0.w,x1.x,x1.y,x1.z,x1.w};
#pragma unroll
        for (int mm = 0; mm < 8; ++mm) {
          float z = tanh_fast(xf[mm] + yf[mm]);
          lp = fmaf(z, vf[mm], lp);
        }
      }
      lpart[half][q][tq] = lp;
    }
    __syncthreads();

    // ---- softmax over t (wave 0 of each half) ----
    if (j < 64) {
      const int t = j;
      float l = lpart[half][0][t] + lpart[half][1][t]
              + lpart[half][2][t] + lpart[half][3][t];
      float mx = l;
#pragma unroll
      for (int off = 32; off; off >>= 1) mx = fmaxf(mx, __shfl_xor(mx, off, 64));
      float e = __builtin_amdgcn_exp2f((l - mx) * 1.4426950408889634f);
      float sm = e;
#pragma unroll
      for (int off = 32; off; off >>= 1) sm += __shfl_xor(sm, off, 64);
      betas[half][t] = e * __builtin_amdgcn_rcpf(sm);
    }
    __syncthreads();

    // ---- Phase B2: ct[m] = sum_t beta[t] * E[b,t,m] ----
    {
      const size_t ebase = (size_t)b * TT * MM + j;
      float acc = 0.f;
#pragma unroll 8
      for (int t = 0; t < TT; ++t)
        acc = fmaf(betas[half][t], GIO<MODE>::ld(E, ebase + (size_t)t * MM), acc);
      ctx[half][j] = acc;
    }
    // ---- y_til = ct.wt + y_t*wt[M] + wt_b (own-value reduce) ----
    {
      float p = ctx[half][j] * GIO<MODE>::ld(wt_w, j);
#pragma unroll
      for (int off = 32; off; off >>= 1) p += __shfl_xor(p, off, 64);
      if ((j & 63) == 0) red[half][j >> 6] = p;
    }
    __syncthreads();
    if (j == 0) {
      float s  = red[half][0] + red[half][1] + red[half][2] + red[half][3];
      float yv = GIO<MODE>::ld(yin, (size_t)b * TT + step);
      ytil_s[half] = s + yv * GIO<MODE>::ld(wt_w, MM) + GIO<MODE>::ld(wt_b, 0);
    }
    __syncthreads();

    // ---- Phase C ----
    lstm_step();
  }

  // ================= finals =================
  {
    float p = ctx[half][j] * GIO<MODE>::ld(wt_w, j);
#pragma unroll
    for (int off = 32; off; off >>= 1) p += __shfl_xor(p, off, 64);
    if ((j & 63) == 0) red[half][j >> 6] = p;
  }
  __syncthreads();
  if (j == 0)
    sc[half][1] = red[half][0] + red[half][1] + red[half][2] + red[half][3];
  __syncthreads();

  head_store(0);  // y_Tp1 (kept in sc[half][0] for train==0 path)

  const int tr = train[0];
  for (int e = 0; e < 2; ++e) {
    if (j == 0) {
      float inp = tr ? GIO<MODE>::ld(tar, (size_t)b * 2 + e) : sc[half][0];
      ytil_s[half] = sc[half][1] + inp * GIO<MODE>::ld(wt_w, MM)
                   + GIO<MODE>::ld(wt_b, 0);
    }
    __syncthreads();
    lstm_step();
    head_store(1 + e);
  }
}

extern "C" void kernel_launch(void* const* d_in, const int* in_sizes, int n_in,
                              void* d_out, int out_size, void* d_ws, size_t ws_size,
                              hipStream_t stream) {
  const void* E     = d_in[0];
  const void* yin   = d_in[1];
  const void* tar   = d_in[2];
  const int*  train = (const int*)d_in[3];
  const void* Wd_w  = d_in[4];
  const void* Wd_b  = d_in[5];
  const void* Ud_w  = d_in[6];
  const void* vd_w  = d_in[7];
  const void* wt_w  = d_in[8];
  const void* wt_b  = d_in[9];
  const void* Wy_w  = d_in[10];
  const void* Wy_b  = d_in[11];
  const void* vy_w  = d_in[12];
  const void* vy_b  = d_in[13];
  const void* Wih   = d_in[14];
  const void* Whh   = d_in[15];
  const void* bih   = d_in[16];
  const void* bhh   = d_in[17];

  float* out = (float*)d_out;

  scan_kernel<0><<<dim3(BB / 2), dim3(512), 0, stream>>>(
      E, yin, tar, train, Wd_w, Wd_b, Ud_w, vd_w, wt_w, wt_b,
      Wy_w, Wy_b, vy_w, vy_b, Wih, Whh, bih, bhh, out);
  scan_kernel<1><<<dim3(BB / 2), dim3(512), 0, stream>>>(
      E, yin, tar, train, Wd_w, Wd_b, Ud_w, vd_w, wt_w, wt_b,
      Wy_w, Wy_b, vy_w, vy_b, Wih, Whh, bih, bhh, out);

  (void)in_sizes; (void)n_in; (void)out_size; (void)d_ws; (void)ws_size;
}

// Round 6
// 2417.326 us; speedup vs baseline: 1.5491x; 1.5491x over previous
//
#include <hip/hip_runtime.h>

// TemporalAttentionDecoder_three_step: B=512, T=64, M=P=256.
// ESTABLISHED (R5 PASS, absmax 9.8e-4): inputs float32, output float32.
// R5 counters: VALUBusy 18%, HBM 5%, Occ 24.6% (1WG/CU), LDS-conflicts 6.3e7
//   -> latency-bound on the per-step Wd (512KB) + Whh (1MB) f32 L2 streams;
//      B1's y1l stride-512B reads were 64-way bank-conflicted.
// R6: (1) weights bf16 in d_ws via prep kernel (halve stream bytes; host
//     ws_size check, f32-template fallback), (2) unroll-8 weight k-loops for
//     more in-flight bytes, (3) y1l row stride 256->264 u16 (8-way max).
// Scan: 256 WGs x 512 thr; WG owns 2 batch rows (independent -> no grid sync).
//   A: x1=[h,c]@Wd^T+b (k-split halves; Wd row shared across both rows)
//   B: z=tanh(x1+y1), l=z.vd, softmax_t, ct=beta.E, ytil=ct.wt+y*wt+b
//   C: g=ytil*Wih + h@Whh^T + bias; i,f,g,o gates; h,c update
// State f32 in LDS; math f32; bf16 only y1 staging + (R6) big weights.

typedef unsigned short u16;
typedef unsigned int u32;

#define BB 512
#define TT 64
#define MM 256
#define PP 256
#define YS 264   // y1l row stride in u16 (256 + 8 pad -> 528B, kills 64-way)

// ws layout (u16): Wd16 [0,131072) | Whh16 [131072,393216) | Wy16 [393216,524288)
#define WD16_OFF  0
#define WHH16_OFF 131072
#define WY16_OFF  393216
#define WQ_ELEMS  524288
#define WQ_BYTES  (WQ_ELEMS * 2)

__device__ __forceinline__ float bf2f(u16 v) {
  union { u32 u; float f; } x; x.u = ((u32)v) << 16; return x.f;
}
__device__ __forceinline__ u16 f2bf(float f) {
  union { u32 u; float f; } x; x.f = f;
  return (u16)((x.u + 0x7fffu + ((x.u >> 16) & 1u)) >> 16);
}
__device__ __forceinline__ void unpack8(uint4 v, float f[8]) {
  union { u32 u; float f; } a;
  a.u = v.x << 16;         f[0] = a.f;
  a.u = v.x & 0xffff0000u; f[1] = a.f;
  a.u = v.y << 16;         f[2] = a.f;
  a.u = v.y & 0xffff0000u; f[3] = a.f;
  a.u = v.z << 16;         f[4] = a.f;
  a.u = v.z & 0xffff0000u; f[5] = a.f;
  a.u = v.w << 16;         f[6] = a.f;
  a.u = v.w & 0xffff0000u; f[7] = a.f;
}
__device__ __forceinline__ float tanh_fast(float x) {
  float e = __builtin_amdgcn_exp2f(x * 2.885390081777927f);
  return 1.0f - 2.0f * __builtin_amdgcn_rcpf(1.0f + e);
}
__device__ __forceinline__ float sigmoid_fast(float x) {
  float e = __builtin_amdgcn_exp2f(x * -1.4426950408889634f);
  return __builtin_amdgcn_rcpf(1.0f + e);
}

// big-weight loader: WQ=1 -> bf16 (prepped in ws), WQ=0 -> f32 (fallback)
template <int WQ>
__device__ __forceinline__ void ldw8(const void* p, size_t i, float f[8]) {
  if (WQ) {
    uint4 v = *(const uint4*)((const u16*)p + i);
    unpack8(v, f);
  } else {
    float4 a = *(const float4*)((const float*)p + i);
    float4 b = *(const float4*)((const float*)p + i + 4);
    f[0]=a.x; f[1]=a.y; f[2]=a.z; f[3]=a.w;
    f[4]=b.x; f[5]=b.y; f[6]=b.z; f[7]=b.w;
  }
}

// ---- prep: f32 -> bf16 for the 3 big weights ----
__global__ __launch_bounds__(256) void prep_kernel(
    const float* __restrict__ Wd, const float* __restrict__ Whh,
    const float* __restrict__ Wy, u16* __restrict__ o) {
  int i = blockIdx.x * 256 + threadIdx.x;
  if (i < WHH16_OFF)      o[i] = f2bf(Wd[i]);
  else if (i < WY16_OFF)  o[i] = f2bf(Whh[i - WHH16_OFF]);
  else if (i < WQ_ELEMS)  o[i] = f2bf(Wy[i - WY16_OFF]);
}

// part/gbuf overlay (disjoint, barrier-separated lifetimes)
#define PART(kh, row, n) pg[(kh) * 512 + (row) * 256 + (n)]
#define GBUF(row, n)     pg[(row) * 1024 + (n)]

template <int WQ>
__global__ __launch_bounds__(512) void scan_kernel(
    const float* __restrict__ E,      // (B,T,M)
    const float* __restrict__ yin,    // (B,T,1)
    const float* __restrict__ tar,    // (B,2)
    const int*   __restrict__ train,  // (1)
    const void*  __restrict__ Wd_q,   // (256,512) f32 or bf16
    const float* __restrict__ Wd_b,   // (256)
    const float* __restrict__ Ud_w,   // (256,256)
    const float* __restrict__ vd_w,   // (256)
    const float* __restrict__ wt_w,   // (257)
    const float* __restrict__ wt_b,   // (1)
    const void*  __restrict__ Wy_q,   // (256,512) f32 or bf16
    const float* __restrict__ Wy_b,   // (256)
    const float* __restrict__ vy_w,   // (256)
    const float* __restrict__ vy_b,   // (1)
    const float* __restrict__ Wih,    // (1024)
    const void*  __restrict__ Whh_q,  // (1024,256) f32 or bf16
    const float* __restrict__ bih,    // (1024)
    const float* __restrict__ bhh,    // (1024)
    float* __restrict__ out)          // (3*B) f32
{
  __shared__ __align__(16) u16   y1l[2][TT * YS];   // 67.6KB bf16 y1, padded
  __shared__ __align__(16) float hs[2][2 * PP];     // [row][ h(256) | c(256) ]
  __shared__ __align__(16) float ctx[2][MM];
  __shared__ __align__(16) float x1s[2][MM];
  __shared__ __align__(16) float pg[2048];          // part / gbuf overlay
  __shared__ __align__(16) float lpart[2][4][TT];
  __shared__ __align__(16) float betas[2][TT];
  __shared__ float red[2][8];
  __shared__ float ytil_s[2];
  __shared__ float sc[2][4];   // [0]=last head value, [1]=ct.wt dot

  const int tid  = threadIdx.x;
  const int half = tid >> 8;       // which of the WG's 2 batch rows
  const int j    = tid & 255;
  const int b    = blockIdx.x * 2 + half;

  for (int i = tid; i < 2 * 2 * PP; i += 512) (&hs[0][0])[i] = 0.f;
  float creg = 0.f;

  // ---- y1 into LDS: thread (half, j) computes column j for all t ----
  {
    const float* __restrict__ Eb = E + (size_t)b * TT * MM;
    const float* __restrict__ Uj = Ud_w + (size_t)j * MM;
    for (int t0 = 0; t0 < TT; t0 += 16) {
      float acc[16];
#pragma unroll
      for (int i = 0; i < 16; ++i) acc[i] = 0.f;
      for (int m0 = 0; m0 < MM; m0 += 8) {
        float w[8]; ldw8<0>(Uj, m0, w);
#pragma unroll
        for (int tt = 0; tt < 16; ++tt) {
          float e[8]; ldw8<0>(Eb, (size_t)(t0 + tt) * MM + m0, e);
#pragma unroll
          for (int mm = 0; mm < 8; ++mm) acc[tt] = fmaf(e[mm], w[mm], acc[tt]);
        }
      }
#pragma unroll
      for (int tt = 0; tt < 16; ++tt)
        y1l[half][(t0 + tt) * YS + j] = f2bf(acc[tt]);
    }
  }
  __syncthreads();

  auto lstm_step = [&]() {
    {
      const int n1 = tid, n2 = tid + 512;
      float a00 = 0.f, a01 = 0.f, a10 = 0.f, a11 = 0.f;
#pragma unroll 8
      for (int k0 = 0; k0 < PP; k0 += 8) {
        float f1[8], f2[8];
        ldw8<WQ>(Whh_q, (size_t)n1 * PP + k0, f1);
        ldw8<WQ>(Whh_q, (size_t)n2 * PP + k0, f2);
        float4 p0 = *(const float4*)&hs[0][k0];
        float4 p1 = *(const float4*)&hs[0][k0 + 4];
        float4 q0 = *(const float4*)&hs[1][k0];
        float4 q1 = *(const float4*)&hs[1][k0 + 4];
        float h0[8] = {p0.x,p0.y,p0.z,p0.w,p1.x,p1.y,p1.z,p1.w};
        float h1[8] = {q0.x,q0.y,q0.z,q0.w,q1.x,q1.y,q1.z,q1.w};
#pragma unroll
        for (int kk = 0; kk < 8; ++kk) {
          a00 = fmaf(h0[kk], f1[kk], a00);
          a01 = fmaf(h1[kk], f1[kk], a01);
          a10 = fmaf(h0[kk], f2[kk], a10);
          a11 = fmaf(h1[kk], f2[kk], a11);
        }
      }
      const float bs1 = bih[n1] + bhh[n1];
      const float bs2 = bih[n2] + bhh[n2];
      const float wi1 = Wih[n1];
      const float wi2 = Wih[n2];
      const float yt0 = ytil_s[0], yt1 = ytil_s[1];
      GBUF(0, n1) = a00 + yt0 * wi1 + bs1;
      GBUF(1, n1) = a01 + yt1 * wi1 + bs1;
      GBUF(0, n2) = a10 + yt0 * wi2 + bs2;
      GBUF(1, n2) = a11 + yt1 * wi2 + bs2;
    }
    __syncthreads();
    {
      // torch LSTMCell gate order i,f,g,o
      float gi = GBUF(half, j);
      float gf = GBUF(half, j + 256);
      float gg = GBUF(half, j + 512);
      float go = GBUF(half, j + 768);
      float c = sigmoid_fast(gf) * creg + sigmoid_fast(gi) * tanh_fast(gg);
      float h = sigmoid_fast(go) * tanh_fast(c);
      creg = c;
      hs[half][j]      = h;
      hs[half][PP + j] = c;
    }
    __syncthreads();
  };

  auto head_store = [&](int outIdx) {
    {
      const int n = tid & 255, kh = tid >> 8;
      const size_t wbase = (size_t)n * 512 + (size_t)kh * 256;
      const float* __restrict__ s0 = kh ? &ctx[0][0] : &hs[0][0];
      const float* __restrict__ s1 = kh ? &ctx[1][0] : &hs[1][0];
      float p0 = 0.f, p1 = 0.f;
#pragma unroll 8
      for (int k0 = 0; k0 < 256; k0 += 8) {
        float w[8]; ldw8<WQ>(Wy_q, wbase + k0, w);
        float4 a0 = *(const float4*)&s0[k0];
        float4 a1 = *(const float4*)&s0[k0 + 4];
        float4 b0 = *(const float4*)&s1[k0];
        float4 b1 = *(const float4*)&s1[k0 + 4];
        float A [8] = {a0.x,a0.y,a0.z,a0.w,a1.x,a1.y,a1.z,a1.w};
        float Bv[8] = {b0.x,b0.y,b0.z,b0.w,b1.x,b1.y,b1.z,b1.w};
#pragma unroll
        for (int kk = 0; kk < 8; ++kk) {
          p0 = fmaf(A[kk],  w[kk], p0);
          p1 = fmaf(Bv[kk], w[kk], p1);
        }
      }
      PART(kh, 0, n) = p0;
      PART(kh, 1, n) = p1;
    }
    __syncthreads();
    {
      float hp = PART(0, half, j) + PART(1, half, j) + Wy_b[j];
      float pp = hp * vy_w[j];
#pragma unroll
      for (int off = 32; off; off >>= 1) pp += __shfl_xor(pp, off, 64);
      if ((j & 63) == 0) red[half][j >> 6] = pp;
    }
    __syncthreads();
    if (j == 0) {
      float o = red[half][0] + red[half][1] + red[half][2] + red[half][3]
              + vy_b[0];
      out[(size_t)outIdx * BB + b] = o;
      sc[half][0] = o;
    }
    __syncthreads();
  };

  // ================= scan over T steps =================
  for (int step = 0; step < TT; ++step) {
    // ---- Phase A: x1 = concat[h,c] @ Wd^T + Wd_b ----
    {
      const int n = tid & 255, kh = tid >> 8;  // k-half: kh=0->h, 1->c
      const size_t wbase = (size_t)n * 512 + (size_t)kh * 256;
      const float* __restrict__ s0 = &hs[0][kh * 256];
      const float* __restrict__ s1 = &hs[1][kh * 256];
      float p0 = 0.f, p1 = 0.f;
#pragma unroll 8
      for (int k0 = 0; k0 < 256; k0 += 8) {
        float w[8]; ldw8<WQ>(Wd_q, wbase + k0, w);
        float4 a0 = *(const float4*)&s0[k0];
        float4 a1 = *(const float4*)&s0[k0 + 4];
        float4 b0 = *(const float4*)&s1[k0];
        float4 b1 = *(const float4*)&s1[k0 + 4];
        float A [8] = {a0.x,a0.y,a0.z,a0.w,a1.x,a1.y,a1.z,a1.w};
        float Bv[8] = {b0.x,b0.y,b0.z,b0.w,b1.x,b1.y,b1.z,b1.w};
#pragma unroll
        for (int kk = 0; kk < 8; ++kk) {
          p0 = fmaf(A[kk],  w[kk], p0);
          p1 = fmaf(Bv[kk], w[kk], p1);
        }
      }
      PART(kh, 0, n) = p0;
      PART(kh, 1, n) = p1;
    }
    __syncthreads();
    x1s[half][j] = PART(0, half, j) + PART(1, half, j) + Wd_b[j];
    __syncthreads();

    // ---- Phase B1: l[t] partials over m-quarters (y1 from LDS, padded) ----
    {
      const int q = j >> 6, tq = j & 63;   // thread = (m-quarter, t)
      const u16* __restrict__ yrow = &y1l[half][tq * YS + q * 64];
      const float* __restrict__ xp = &x1s[half][q * 64];
      const float* __restrict__ vp = vd_w + q * 64;
      float lp = 0.f;
#pragma unroll 2
      for (int m0 = 0; m0 < 64; m0 += 8) {
        uint4 yv = *(const uint4*)(yrow + m0);
        float yf[8]; unpack8(yv, yf);
        float4 v0 = *(const float4*)&vp[m0];
        float4 v1 = *(const float4*)&vp[m0 + 4];
        float vf[8] = {v0.x,v0.y,v0.z,v0.w,v1.x,v1.y,v1.z,v1.w};
        float4 x0 = *(const float4*)&xp[m0];
        float4 x1 = *(const float4*)&xp[m0 + 4];
        float xf[8] = {x0.x,x0.y,x0.z,x0.w,x1.x,x1.y,x1.z,x1.w};
#pragma unroll
        for (int mm = 0; mm < 8; ++mm) {
          float z = tanh_fast(xf[mm] + yf[mm]);
          lp = fmaf(z, vf[mm], lp);
        }
      }
      lpart[half][q][tq] = lp;
    }
    __syncthreads();

    // ---- softmax over t (wave 0 of each half) ----
    if (j < 64) {
      const int t = j;
      float l = lpart[half][0][t] + lpart[half][1][t]
              + lpart[half][2][t] + lpart[half][3][t];
      float mx = l;
#pragma unroll
      for (int off = 32; off; off >>= 1) mx = fmaxf(mx, __shfl_xor(mx, off, 64));
      float e = __builtin_amdgcn_exp2f((l - mx) * 1.4426950408889634f);
      float sm = e;
#pragma unroll
      for (int off = 32; off; off >>= 1) sm += __shfl_xor(sm, off, 64);
      betas[half][t] = e * __builtin_amdgcn_rcpf(sm);
    }
    __syncthreads();

    // ---- Phase B2: ct[m] = sum_t beta[t] * E[b,t,m] ----
    {
      const float* __restrict__ ec = E + (size_t)b * TT * MM + j;
      float acc = 0.f;
#pragma unroll 16
      for (int t = 0; t < TT; ++t)
        acc = fmaf(betas[half][t], ec[(size_t)t * MM], acc);
      ctx[half][j] = acc;
    }
    // ---- y_til = ct.wt + y_t*wt[M] + wt_b (own-value reduce) ----
    {
      float p = ctx[half][j] * wt_w[j];
#pragma unroll
      for (int off = 32; off; off >>= 1) p += __shfl_xor(p, off, 64);
      if ((j & 63) == 0) red[half][j >> 6] = p;
    }
    __syncthreads();
    if (j == 0) {
      float s  = red[half][0] + red[half][1] + red[half][2] + red[half][3];
      float yv = yin[(size_t)b * TT + step];
      ytil_s[half] = s + yv * wt_w[MM] + wt_b[0];
    }
    __syncthreads();

    // ---- Phase C ----
    lstm_step();
  }

  // ================= finals =================
  {
    float p = ctx[half][j] * wt_w[j];
#pragma unroll
    for (int off = 32; off; off >>= 1) p += __shfl_xor(p, off, 64);
    if ((j & 63) == 0) red[half][j >> 6] = p;
  }
  __syncthreads();
  if (j == 0)
    sc[half][1] = red[half][0] + red[half][1] + red[half][2] + red[half][3];
  __syncthreads();

  head_store(0);  // y_Tp1 (kept in sc[half][0] for train==0 path)

  const int tr = train[0];
  for (int e = 0; e < 2; ++e) {
    if (j == 0) {
      float inp = tr ? tar[(size_t)b * 2 + e] : sc[half][0];
      ytil_s[half] = sc[half][1] + inp * wt_w[MM] + wt_b[0];
    }
    __syncthreads();
    lstm_step();
    head_store(1 + e);
  }
}

extern "C" void kernel_launch(void* const* d_in, const int* in_sizes, int n_in,
                              void* d_out, int out_size, void* d_ws, size_t ws_size,
                              hipStream_t stream) {
  const float* E     = (const float*)d_in[0];
  const float* yin   = (const float*)d_in[1];
  const float* tar   = (const float*)d_in[2];
  const int*   train = (const int*)d_in[3];
  const float* Wd_w  = (const float*)d_in[4];
  const float* Wd_b  = (const float*)d_in[5];
  const float* Ud_w  = (const float*)d_in[6];
  const float* vd_w  = (const float*)d_in[7];
  const float* wt_w  = (const float*)d_in[8];
  const float* wt_b  = (const float*)d_in[9];
  const float* Wy_w  = (const float*)d_in[10];
  const float* Wy_b  = (const float*)d_in[11];
  const float* vy_w  = (const float*)d_in[12];
  const float* vy_b  = (const float*)d_in[13];
  const float* Wih   = (const float*)d_in[14];
  const float* Whh   = (const float*)d_in[15];
  const float* bih   = (const float*)d_in[16];
  const float* bhh   = (const float*)d_in[17];

  float* out = (float*)d_out;

  if (ws_size >= (size_t)WQ_BYTES) {
    u16* wq = (u16*)d_ws;
    prep_kernel<<<dim3(WQ_ELEMS / 256), dim3(256), 0, stream>>>(
        Wd_w, Whh, Wy_w, wq);
    scan_kernel<1><<<dim3(BB / 2), dim3(512), 0, stream>>>(
        E, yin, tar, train, wq + WD16_OFF, Wd_b, Ud_w, vd_w, wt_w, wt_b,
        wq + WY16_OFF, Wy_b, vy_w, vy_b, Wih, wq + WHH16_OFF, bih, bhh, out);
  } else {
    scan_kernel<0><<<dim3(BB / 2), dim3(512), 0, stream>>>(
        E, yin, tar, train, Wd_w, Wd_b, Ud_w, vd_w, wt_w, wt_b,
        Wy_w, Wy_b, vy_w, vy_b, Wih, Whh, bih, bhh, out);
  }

  (void)in_sizes; (void)n_in; (void)out_size;
}

// Round 7
// 2177.220 us; speedup vs baseline: 1.7199x; 1.1103x over previous
//
#include <hip/hip_runtime.h>

// TemporalAttentionDecoder_three_step: B=512, T=64, M=P=256. in f32, out f32.
// R6: 2417us, VALU 33%, FETCH 1.46GB (unchanged vs R5) -> HBM stream = Phase
//     B2 re-reading E every step (L2 thrash: 32 WG x 128KB/step = 4MB/XCD).
// R7: (1) stage E slice in LDS as bf16 (64KB/WG) once; B2 = LDS reads ->
//         per-step global traffic becomes weights-only (L2-resident).
//     (2) fuse Phase A (Wd@[h,c]) + LSTM matvec (Whh@h) into ONE stream
//         phase: 3 units x 2 rows = 6 independent k=256 dots/thread (ILP);
//         ytil*Wih + biases deferred to gate stage. One fewer barrier.
// Scan: 256 WGs x 512 thr; WG owns 2 batch rows. LDS ~153KB, 1 WG/CU.

typedef unsigned short u16;
typedef unsigned int u32;

#define BB 512
#define TT 64
#define MM 256
#define PP 256
#define YS 264   // y1l row stride in u16 (pad: kills 16/64-way conflicts)

// ws layout (u16): Wd16 [0,131072) | Whh16 [131072,393216) | Wy16 [393216,524288)
#define WD16_OFF  0
#define WHH16_OFF 131072
#define WY16_OFF  393216
#define WQ_ELEMS  524288
#define WQ_BYTES  (WQ_ELEMS * 2)

__device__ __forceinline__ float bf2f(u16 v) {
  union { u32 u; float f; } x; x.u = ((u32)v) << 16; return x.f;
}
__device__ __forceinline__ u16 f2bf(float f) {
  union { u32 u; float f; } x; x.f = f;
  return (u16)((x.u + 0x7fffu + ((x.u >> 16) & 1u)) >> 16);
}
__device__ __forceinline__ void unpack8(uint4 v, float f[8]) {
  union { u32 u; float f; } a;
  a.u = v.x << 16;         f[0] = a.f;
  a.u = v.x & 0xffff0000u; f[1] = a.f;
  a.u = v.y << 16;         f[2] = a.f;
  a.u = v.y & 0xffff0000u; f[3] = a.f;
  a.u = v.z << 16;         f[4] = a.f;
  a.u = v.z & 0xffff0000u; f[5] = a.f;
  a.u = v.w << 16;         f[6] = a.f;
  a.u = v.w & 0xffff0000u; f[7] = a.f;
}
__device__ __forceinline__ float tanh_fast(float x) {
  float e = __builtin_amdgcn_exp2f(x * 2.885390081777927f);
  return 1.0f - 2.0f * __builtin_amdgcn_rcpf(1.0f + e);
}
__device__ __forceinline__ float sigmoid_fast(float x) {
  float e = __builtin_amdgcn_exp2f(x * -1.4426950408889634f);
  return __builtin_amdgcn_rcpf(1.0f + e);
}

// big-weight loader: WQ=1 -> bf16 (prepped in ws), WQ=0 -> f32 (fallback)
template <int WQ>
__device__ __forceinline__ void ldw8(const void* p, size_t i, float f[8]) {
  if (WQ) {
    uint4 v = *(const uint4*)((const u16*)p + i);
    unpack8(v, f);
  } else {
    float4 a = *(const float4*)((const float*)p + i);
    float4 b = *(const float4*)((const float*)p + i + 4);
    f[0]=a.x; f[1]=a.y; f[2]=a.z; f[3]=a.w;
    f[4]=b.x; f[5]=b.y; f[6]=b.z; f[7]=b.w;
  }
}

// ---- prep: f32 -> bf16 for the 3 big weights ----
__global__ __launch_bounds__(256) void prep_kernel(
    const float* __restrict__ Wd, const float* __restrict__ Whh,
    const float* __restrict__ Wy, u16* __restrict__ o) {
  int i = blockIdx.x * 256 + threadIdx.x;
  if (i < WHH16_OFF)      o[i] = f2bf(Wd[i]);
  else if (i < WY16_OFF)  o[i] = f2bf(Whh[i - WHH16_OFF]);
  else if (i < WQ_ELEMS)  o[i] = f2bf(Wy[i - WY16_OFF]);
}

#define PART(kh, row, n) part[(kh) * 512 + (row) * 256 + (n)]
#define GB(row, n)       gbuf[(row) * 1024 + (n)]

template <int WQ>
__global__ __launch_bounds__(512, 2) void scan_kernel(
    const float* __restrict__ E,      // (B,T,M)
    const float* __restrict__ yin,    // (B,T,1)
    const float* __restrict__ tar,    // (B,2)
    const int*   __restrict__ train,  // (1)
    const void*  __restrict__ Wd_q,   // (256,512) f32 or bf16
    const float* __restrict__ Wd_b,   // (256)
    const float* __restrict__ Ud_w,   // (256,256)
    const float* __restrict__ vd_w,   // (256)
    const float* __restrict__ wt_w,   // (257)
    const float* __restrict__ wt_b,   // (1)
    const void*  __restrict__ Wy_q,   // (256,512) f32 or bf16
    const float* __restrict__ Wy_b,   // (256)
    const float* __restrict__ vy_w,   // (256)
    const float* __restrict__ vy_b,   // (1)
    const float* __restrict__ Wih,    // (1024)
    const void*  __restrict__ Whh_q,  // (1024,256) f32 or bf16
    const float* __restrict__ bih,    // (1024)
    const float* __restrict__ bhh,    // (1024)
    float* __restrict__ out)          // (3*B) f32
{
  __shared__ __align__(16) u16   y1l[2][TT * YS];   // 67.6KB bf16 y1, padded
  __shared__ __align__(16) u16   e16[2][TT * MM];   // 64KB bf16 E slice
  __shared__ __align__(16) float hs[2][2 * PP];     // [row][ h(256) | c(256) ]
  __shared__ __align__(16) float ctx[2][MM];
  __shared__ __align__(16) float x1s[2][MM];
  __shared__ __align__(16) float part[1024];        // x1 k-half partials
  __shared__ __align__(16) float gbuf[2048];        // LSTM matvec partials
  __shared__ __align__(16) float lpart[2][4][TT];
  __shared__ __align__(16) float betas[2][TT];
  __shared__ float red[2][8];
  __shared__ float ytil_s[2];
  __shared__ float sc[2][4];   // [0]=last head value, [1]=ct.wt dot

  const int tid  = threadIdx.x;
  const int half = tid >> 8;       // which of the WG's 2 batch rows
  const int j    = tid & 255;
  const int b    = blockIdx.x * 2 + half;

  for (int i = tid; i < 2 * 2 * PP; i += 512) (&hs[0][0])[i] = 0.f;
  float creg = 0.f;

  // ---- stage E slice -> LDS bf16 (one-time). 16384 u32 pair-stores. ----
  {
    const float2* __restrict__ E2 = (const float2*)(E + (size_t)blockIdx.x * 2 * TT * MM);
    u32* __restrict__ ed = (u32*)&e16[0][0];
    for (int i = tid; i < 2 * TT * MM / 2; i += 512) {
      float2 v = E2[i];
      ed[i] = (u32)f2bf(v.x) | ((u32)f2bf(v.y) << 16);
    }
  }

  // ---- y1 into LDS: thread (half, j) computes column j for all t ----
  {
    const float* __restrict__ Eb = E + (size_t)b * TT * MM;
    const float* __restrict__ Uj = Ud_w + (size_t)j * MM;
    for (int t0 = 0; t0 < TT; t0 += 16) {
      float acc[16];
#pragma unroll
      for (int i = 0; i < 16; ++i) acc[i] = 0.f;
      for (int m0 = 0; m0 < MM; m0 += 8) {
        float w[8]; ldw8<0>(Uj, m0, w);
#pragma unroll
        for (int tt = 0; tt < 16; ++tt) {
          float e[8]; ldw8<0>(Eb, (size_t)(t0 + tt) * MM + m0, e);
#pragma unroll
          for (int mm = 0; mm < 8; ++mm) acc[tt] = fmaf(e[mm], w[mm], acc[tt]);
        }
      }
#pragma unroll
      for (int tt = 0; tt < 16; ++tt)
        y1l[half][(t0 + tt) * YS + j] = f2bf(acc[tt]);
    }
  }
  __syncthreads();

  // ---- LSTM matvec only (used by the 2 extra steps): gbuf = Whh@h ----
  auto lstm_mv = [&]() {
    const int n1 = tid, n2 = tid + 512;
    float a00 = 0.f, a01 = 0.f, a10 = 0.f, a11 = 0.f;
#pragma unroll 8
    for (int k0 = 0; k0 < PP; k0 += 8) {
      float f1[8], f2[8];
      ldw8<WQ>(Whh_q, (size_t)n1 * PP + k0, f1);
      ldw8<WQ>(Whh_q, (size_t)n2 * PP + k0, f2);
      float4 p0 = *(const float4*)&hs[0][k0];
      float4 p1 = *(const float4*)&hs[0][k0 + 4];
      float4 q0 = *(const float4*)&hs[1][k0];
      float4 q1 = *(const float4*)&hs[1][k0 + 4];
      float h0[8] = {p0.x,p0.y,p0.z,p0.w,p1.x,p1.y,p1.z,p1.w};
      float h1[8] = {q0.x,q0.y,q0.z,q0.w,q1.x,q1.y,q1.z,q1.w};
#pragma unroll
      for (int kk = 0; kk < 8; ++kk) {
        a00 = fmaf(h0[kk], f1[kk], a00);
        a01 = fmaf(h1[kk], f1[kk], a01);
        a10 = fmaf(h0[kk], f2[kk], a10);
        a11 = fmaf(h1[kk], f2[kk], a11);
      }
    }
    GB(0, n1) = a00; GB(1, n1) = a01;
    GB(0, n2) = a10; GB(1, n2) = a11;
  };

  // ---- gates: consume gbuf + ytil_s; Wih/bias folded here (L1-hot) ----
  auto lstm_gates = [&]() {
    const float yt = ytil_s[half];
    float gi = GB(half, j)       + yt * Wih[j]       + bih[j]       + bhh[j];
    float gf = GB(half, j + 256) + yt * Wih[j + 256] + bih[j + 256] + bhh[j + 256];
    float gg = GB(half, j + 512) + yt * Wih[j + 512] + bih[j + 512] + bhh[j + 512];
    float go = GB(half, j + 768) + yt * Wih[j + 768] + bih[j + 768] + bhh[j + 768];
    float c = sigmoid_fast(gf) * creg + sigmoid_fast(gi) * tanh_fast(gg);
    float h = sigmoid_fast(go) * tanh_fast(c);
    creg = c;
    hs[half][j]      = h;
    hs[half][PP + j] = c;
  };

  auto head_store = [&](int outIdx) {
    {
      const int n = tid & 255, kh = tid >> 8;
      const size_t wbase = (size_t)n * 512 + (size_t)kh * 256;
      const float* __restrict__ s0 = kh ? &ctx[0][0] : &hs[0][0];
      const float* __restrict__ s1 = kh ? &ctx[1][0] : &hs[1][0];
      float p0 = 0.f, p1 = 0.f;
#pragma unroll 8
      for (int k0 = 0; k0 < 256; k0 += 8) {
        float w[8]; ldw8<WQ>(Wy_q, wbase + k0, w);
        float4 a0 = *(const float4*)&s0[k0];
        float4 a1 = *(const float4*)&s0[k0 + 4];
        float4 b0 = *(const float4*)&s1[k0];
        float4 b1 = *(const float4*)&s1[k0 + 4];
        float A [8] = {a0.x,a0.y,a0.z,a0.w,a1.x,a1.y,a1.z,a1.w};
        float Bv[8] = {b0.x,b0.y,b0.z,b0.w,b1.x,b1.y,b1.z,b1.w};
#pragma unroll
        for (int kk = 0; kk < 8; ++kk) {
          p0 = fmaf(A[kk],  w[kk], p0);
          p1 = fmaf(Bv[kk], w[kk], p1);
        }
      }
      PART(kh, 0, n) = p0;
      PART(kh, 1, n) = p1;
    }
    __syncthreads();
    {
      float hp = PART(0, half, j) + PART(1, half, j) + Wy_b[j];
      float pp = hp * vy_w[j];
#pragma unroll
      for (int off = 32; off; off >>= 1) pp += __shfl_xor(pp, off, 64);
      if ((j & 63) == 0) red[half][j >> 6] = pp;
    }
    __syncthreads();
    if (j == 0) {
      float o = red[half][0] + red[half][1] + red[half][2] + red[half][3]
              + vy_b[0];
      out[(size_t)outIdx * BB + b] = o;
      sc[half][0] = o;
    }
    __syncthreads();
  };

  // ================= scan over T steps =================
  for (int step = 0; step < TT; ++step) {
    // ---- FUSED stream phase: x1 partials (Wd@[h,c]) + gbuf (Whh@h) ----
    // 3 units x 2 rows = 6 independent k=256 dot streams per thread.
    {
      const int n = tid & 255, kh = tid >> 8;
      const size_t wdb = (size_t)n * 512 + (size_t)kh * 256;
      const size_t w1b = (size_t)tid * PP;
      const size_t w2b = (size_t)(tid + 512) * PP;
      const float* __restrict__ sA0 = &hs[0][kh * 256];
      const float* __restrict__ sA1 = &hs[1][kh * 256];
      const float* __restrict__ sH0 = &hs[0][0];
      const float* __restrict__ sH1 = &hs[1][0];
      float ax0 = 0.f, ax1 = 0.f;
      float b10 = 0.f, b11 = 0.f, b20 = 0.f, b21 = 0.f;
#pragma unroll 4
      for (int k0 = 0; k0 < 256; k0 += 8) {
        float wd[8], w1[8], w2[8];
        ldw8<WQ>(Wd_q,  wdb + k0, wd);
        ldw8<WQ>(Whh_q, w1b + k0, w1);
        ldw8<WQ>(Whh_q, w2b + k0, w2);
        float4 a0 = *(const float4*)&sA0[k0];
        float4 a1 = *(const float4*)&sA0[k0 + 4];
        float4 c0 = *(const float4*)&sA1[k0];
        float4 c1 = *(const float4*)&sA1[k0 + 4];
        float4 h0 = *(const float4*)&sH0[k0];
        float4 h1 = *(const float4*)&sH0[k0 + 4];
        float4 g0 = *(const float4*)&sH1[k0];
        float4 g1 = *(const float4*)&sH1[k0 + 4];
        float A0[8] = {a0.x,a0.y,a0.z,a0.w,a1.x,a1.y,a1.z,a1.w};
        float A1[8] = {c0.x,c0.y,c0.z,c0.w,c1.x,c1.y,c1.z,c1.w};
        float H0[8] = {h0.x,h0.y,h0.z,h0.w,h1.x,h1.y,h1.z,h1.w};
        float H1[8] = {g0.x,g0.y,g0.z,g0.w,g1.x,g1.y,g1.z,g1.w};
#pragma unroll
        for (int kk = 0; kk < 8; ++kk) {
          ax0 = fmaf(A0[kk], wd[kk], ax0);
          ax1 = fmaf(A1[kk], wd[kk], ax1);
          b10 = fmaf(H0[kk], w1[kk], b10);
          b11 = fmaf(H1[kk], w1[kk], b11);
          b20 = fmaf(H0[kk], w2[kk], b20);
          b21 = fmaf(H1[kk], w2[kk], b21);
        }
      }
      PART(kh, 0, n) = ax0;
      PART(kh, 1, n) = ax1;
      GB(0, tid) = b10;       GB(1, tid) = b11;
      GB(0, tid + 512) = b20; GB(1, tid + 512) = b21;
    }
    __syncthreads();
    x1s[half][j] = PART(0, half, j) + PART(1, half, j) + Wd_b[j];
    __syncthreads();

    // ---- Phase B1: l[t] partials over m-quarters (y1 from LDS, padded) ----
    {
      const int q = j >> 6, tq = j & 63;   // thread = (m-quarter, t)
      const u16* __restrict__ yrow = &y1l[half][tq * YS + q * 64];
      const float* __restrict__ xp = &x1s[half][q * 64];
      const float* __restrict__ vp = vd_w + q * 64;
      float lp = 0.f;
#pragma unroll 2
      for (int m0 = 0; m0 < 64; m0 += 8) {
        uint4 yv = *(const uint4*)(yrow + m0);
        float yf[8]; unpack8(yv, yf);
        float4 v0 = *(const float4*)&vp[m0];
        float4 v1 = *(const float4*)&vp[m0 + 4];
        float vf[8] = {v0.x,v0.y,v0.z,v0.w,v1.x,v1.y,v1.z,v1.w};
        float4 x0 = *(const float4*)&xp[m0];
        float4 x1 = *(const float4*)&xp[m0 + 4];
        float xf[8] = {x0.x,x0.y,x0.z,x0.w,x1.x,x1.y,x1.z,x1.w};
#pragma unroll
        for (int mm = 0; mm < 8; ++mm) {
          float z = tanh_fast(xf[mm] + yf[mm]);
          lp = fmaf(z, vf[mm], lp);
        }
      }
      lpart[half][q][tq] = lp;
    }
    __syncthreads();

    // ---- softmax over t (wave 0 of each half) ----
    if (j < 64) {
      const int t = j;
      float l = lpart[half][0][t] + lpart[half][1][t]
              + lpart[half][2][t] + lpart[half][3][t];
      float mx = l;
#pragma unroll
      for (int off = 32; off; off >>= 1) mx = fmaxf(mx, __shfl_xor(mx, off, 64));
      float e = __builtin_amdgcn_exp2f((l - mx) * 1.4426950408889634f);
      float sm = e;
#pragma unroll
      for (int off = 32; off; off >>= 1) sm += __shfl_xor(sm, off, 64);
      betas[half][t] = e * __builtin_amdgcn_rcpf(sm);
    }
    __syncthreads();

    // ---- Phase B2: ct[m] = sum_t beta[t] * E_lds[t,m] (bf16 LDS) ----
    {
      const u16* __restrict__ ec = &e16[half][j];
      float acc = 0.f;
#pragma unroll 16
      for (int t = 0; t < TT; ++t)
        acc = fmaf(betas[half][t], bf2f(ec[t * MM]), acc);
      ctx[half][j] = acc;
    }
    // ---- y_til = ct.wt + y_t*wt[M] + wt_b (own-value reduce) ----
    {
      float p = ctx[half][j] * wt_w[j];
#pragma unroll
      for (int off = 32; off; off >>= 1) p += __shfl_xor(p, off, 64);
      if ((j & 63) == 0) red[half][j >> 6] = p;
    }
    __syncthreads();
    if (j == 0) {
      float s  = red[half][0] + red[half][1] + red[half][2] + red[half][3];
      float yv = yin[(size_t)b * TT + step];
      ytil_s[half] = s + yv * wt_w[MM] + wt_b[0];
    }
    __syncthreads();

    // ---- gates (gbuf from fused phase + ytil) ----
    lstm_gates();
    __syncthreads();
  }

  // ================= finals =================
  {
    float p = ctx[half][j] * wt_w[j];
#pragma unroll
    for (int off = 32; off; off >>= 1) p += __shfl_xor(p, off, 64);
    if ((j & 63) == 0) red[half][j >> 6] = p;
  }
  __syncthreads();
  if (j == 0)
    sc[half][1] = red[half][0] + red[half][1] + red[half][2] + red[half][3];
  __syncthreads();

  head_store(0);  // y_Tp1 (kept in sc[half][0] for train==0 path)

  const int tr = train[0];
  for (int e = 0; e < 2; ++e) {
    if (j == 0) {
      float inp = tr ? tar[(size_t)b * 2 + e] : sc[half][0];
      ytil_s[half] = sc[half][1] + inp * wt_w[MM] + wt_b[0];
    }
    __syncthreads();
    lstm_mv();
    __syncthreads();
    lstm_gates();
    __syncthreads();
    head_store(1 + e);
  }
}

extern "C" void kernel_launch(void* const* d_in, const int* in_sizes, int n_in,
                              void* d_out, int out_size, void* d_ws, size_t ws_size,
                              hipStream_t stream) {
  const float* E     = (const float*)d_in[0];
  const float* yin   = (const float*)d_in[1];
  const float* tar   = (const float*)d_in[2];
  const int*   train = (const int*)d_in[3];
  const float* Wd_w  = (const float*)d_in[4];
  const float* Wd_b  = (const float*)d_in[5];
  const float* Ud_w  = (const float*)d_in[6];
  const float* vd_w  = (const float*)d_in[7];
  const float* wt_w  = (const float*)d_in[8];
  const float* wt_b  = (const float*)d_in[9];
  const float* Wy_w  = (const float*)d_in[10];
  const float* Wy_b  = (const float*)d_in[11];
  const float* vy_w  = (const float*)d_in[12];
  const float* vy_b  = (const float*)d_in[13];
  const float* Wih   = (const float*)d_in[14];
  const float* Whh   = (const float*)d_in[15];
  const float* bih   = (const float*)d_in[16];
  const float* bhh   = (const float*)d_in[17];

  float* out = (float*)d_out;

  if (ws_size >= (size_t)WQ_BYTES) {
    u16* wq = (u16*)d_ws;
    prep_kernel<<<dim3(WQ_ELEMS / 256), dim3(256), 0, stream>>>(
        Wd_w, Whh, Wy_w, wq);
    scan_kernel<1><<<dim3(BB / 2), dim3(512), 0, stream>>>(
        E, yin, tar, train, wq + WD16_OFF, Wd_b, Ud_w, vd_w, wt_w, wt_b,
        wq + WY16_OFF, Wy_b, vy_w, vy_b, Wih, wq + WHH16_OFF, bih, bhh, out);
  } else {
    scan_kernel<0><<<dim3(BB / 2), dim3(512), 0, stream>>>(
        E, yin, tar, train, Wd_w, Wd_b, Ud_w, vd_w, wt_w, wt_b,
        Wy_w, Wy_b, vy_w, vy_b, Wih, Whh, bih, bhh, out);
  }

  (void)in_sizes; (void)n_in; (void)out_size;
}

// Round 8
// 1188.931 us; speedup vs baseline: 3.1496x; 1.8312x over previous
//
#include <hip/hip_runtime.h>

// TemporalAttentionDecoder_three_step: B=512, T=64, M=P=256. in f32, out f32.
// R7: 2177us, VALU 41%, HBM 0.3% -> latency-bound; weight stream was
//     row-per-lane (uncoalesced, L1-thrashed ~4x L2 overfetch) + bf16 unpack.
// R8: (1) weights f16 in k-blocked n-major layout [kb][n][8] -> lane-coalesced
//         1KB bursts; (2) v_dot2_f32_f16 (fdot2) -> no unpack, half the MACs;
//     (3) 1 row per 256-thr WG, 2 WGs/CU (LDS ~74KB) -> independent barrier
//         domains overlap; gbuf eliminated (gate writer==reader).
// Per step: stream (Wd@[h,c] -> x1, Whh@h -> 4 regs) | B1 tanh/l | softmax |
//           B2 ct=beta.E (E^T f16 LDS, fdot2) | ytil reduce | gates.
// f32 state: creg (register); f16: h,c,y1,E,ct,weights; dots accumulate f32.

typedef unsigned short u16;
typedef unsigned int u32;
typedef _Float16 half_t;
typedef half_t h2 __attribute__((ext_vector_type(2)));

#define BB 512
#define TT 64
#define MM 256
#define PP 256
#define YS 264   // y1l row stride (u16); 528B, measured conflict-free (R6/R7)
#define ES 68    // e16T row stride (u16); 136B -> 2-way (free)

// ws layout (u16), all k-blocked n-major [kb][n][8]:
//   WdT8 [64kb][256n][8]  @ 0       (131072)
//   WhhT8[32kb][1024n][8] @ 131072  (262144)
//   WyT8 [64kb][256n][8]  @ 393216  (131072)
#define WD16_OFF  0
#define WHH16_OFF 131072
#define WY16_OFF  393216
#define WQ_ELEMS  524288
#define WQ_BYTES  (WQ_ELEMS * 2)

struct H8 { h2 p[4]; };   // 16B = 8 f16

#if defined(__has_builtin)
#if __has_builtin(__builtin_amdgcn_fdot2)
#define FDOT2(a, b, c) __builtin_amdgcn_fdot2((a), (b), (c), false)
#endif
#endif
#ifndef FDOT2
__device__ __forceinline__ float FDOT2(h2 a, h2 b, float c) {
  return c + (float)a[0] * (float)b[0] + (float)a[1] * (float)b[1];
}
#endif

__device__ __forceinline__ float dot8(const H8 w, const H8 a, float acc) {
  acc = FDOT2(w.p[0], a.p[0], acc);
  acc = FDOT2(w.p[1], a.p[1], acc);
  acc = FDOT2(w.p[2], a.p[2], acc);
  acc = FDOT2(w.p[3], a.p[3], acc);
  return acc;
}
__device__ __forceinline__ u16 f2h(float f) {
  union { half_t h; u16 u; } x; x.h = (half_t)f; return x.u;
}
__device__ __forceinline__ void unpackH8(const H8 v, float f[8]) {
#pragma unroll
  for (int i = 0; i < 8; ++i) f[i] = (float)v.p[i >> 1][i & 1];
}
__device__ __forceinline__ void ldf8(const float* p, float f[8]) {
  float4 a = *(const float4*)p;
  float4 b = *(const float4*)(p + 4);
  f[0]=a.x; f[1]=a.y; f[2]=a.z; f[3]=a.w;
  f[4]=b.x; f[5]=b.y; f[6]=b.z; f[7]=b.w;
}
__device__ __forceinline__ float tanh_fast(float x) {
  float e = __builtin_amdgcn_exp2f(x * 2.885390081777927f);
  return 1.0f - 2.0f * __builtin_amdgcn_rcpf(1.0f + e);
}
__device__ __forceinline__ float sigmoid_fast(float x) {
  float e = __builtin_amdgcn_exp2f(x * -1.4426950408889634f);
  return __builtin_amdgcn_rcpf(1.0f + e);
}

// ---- prep: f32 -> f16, k-blocked n-major ----
__global__ __launch_bounds__(256) void prep_kernel(
    const float* __restrict__ Wd, const float* __restrict__ Whh,
    const float* __restrict__ Wy, u16* __restrict__ o) {
  int i = blockIdx.x * 256 + threadIdx.x;   // 0..524287
  float v;
  if (i < WHH16_OFF) {
    int ki = i & 7, n = (i >> 3) & 255, kb = i >> 11;
    v = Wd[n * 512 + kb * 8 + ki];
  } else if (i < WY16_OFF) {
    int r = i - WHH16_OFF;
    int ki = r & 7, n = (r >> 3) & 1023, kb = r >> 13;
    v = Whh[n * 256 + kb * 8 + ki];
  } else {
    int r = i - WY16_OFF;
    int ki = r & 7, n = (r >> 3) & 255, kb = r >> 11;
    v = Wy[n * 512 + kb * 8 + ki];
  }
  o[i] = f2h(v);
}

template <int WQ>
__global__ __launch_bounds__(256, 2) void scan_kernel(
    const float* __restrict__ E,      // (B,T,M)
    const float* __restrict__ yin,    // (B,T,1)
    const float* __restrict__ tar,    // (B,2)
    const int*   __restrict__ train,  // (1)
    const void*  __restrict__ Wd_q,   // WQ1: WdT8 f16 | WQ0: f32 row-major
    const float* __restrict__ Wd_b,
    const float* __restrict__ Ud_w,   // (256,256) f32
    const float* __restrict__ vd_w,
    const float* __restrict__ wt_w,   // (257)
    const float* __restrict__ wt_b,
    const void*  __restrict__ Wy_q,
    const float* __restrict__ Wy_b,
    const float* __restrict__ vy_w,
    const float* __restrict__ vy_b,
    const float* __restrict__ Wih,    // (1024)
    const void*  __restrict__ Whh_q,
    const float* __restrict__ bih,
    const float* __restrict__ bhh,
    float* __restrict__ out)          // (3*B)
{
  __shared__ __align__(16) u16   y1l[TT * YS];     // 33.8KB f16 y1, padded
  __shared__ __align__(16) u16   e16T[MM * ES];    // 34.8KB f16 E^T, padded
  __shared__ __align__(16) u32   hs16[256];        // h pairs [0,128), c [128,256)
  __shared__ __align__(16) u32   ctx16p[128];      // ct f16 pairs
  __shared__ __align__(16) float ctx[MM];
  __shared__ __align__(16) float x1s[MM];
  __shared__ __align__(16) float lpart[4][TT];
  __shared__ __align__(16) u16   betas16[TT];
  __shared__ float red[4];
  __shared__ float sc[2];

  const int j = threadIdx.x;           // 0..255
  const int b = blockIdx.x;            // batch row
  const int wv = j >> 6;               // wave id 0..3

  hs16[j] = 0;
  float creg = 0.f;

  // ---- stage E^T (f16) into LDS: coalesced global read, b16 scatter ----
  {
    const float* __restrict__ Eb = E + (size_t)b * TT * MM;
    for (int i = j; i < TT * MM; i += 256) {
      int t = i >> 8, m = i & 255;
      e16T[m * ES + t] = f2h(Eb[i]);
    }
  }

  // ---- y1 into LDS: thread j computes column j for all 64 t (f32 math) ----
  {
    const float* __restrict__ Eb = E + (size_t)b * TT * MM;
    const float* __restrict__ Uj = Ud_w + (size_t)j * MM;
    for (int t0 = 0; t0 < TT; t0 += 16) {
      float acc[16];
#pragma unroll
      for (int i = 0; i < 16; ++i) acc[i] = 0.f;
      for (int m0 = 0; m0 < MM; m0 += 8) {
        float w[8]; ldf8(Uj + m0, w);
#pragma unroll
        for (int tt = 0; tt < 16; ++tt) {
          float e[8]; ldf8(Eb + (size_t)(t0 + tt) * MM + m0, e);
#pragma unroll
          for (int mm = 0; mm < 8; ++mm) acc[tt] = fmaf(e[mm], w[mm], acc[tt]);
        }
      }
#pragma unroll
      for (int tt = 0; tt < 16; ++tt)
        y1l[(t0 + tt) * YS + j] = f2h(acc[tt]);
    }
  }
  __syncthreads();

  // ---- Whh @ h -> 4 gate pre-activations (registers; writer==reader) ----
  auto mv4 = [&](float& g0, float& g1, float& g2, float& g3) {
    g0 = g1 = g2 = g3 = 0.f;
    if (WQ) {
      const u16* W = (const u16*)Whh_q;
      const u16* p0 = W + (size_t)j * 8;
      const u16* p1 = p0 + 256 * 8;
      const u16* p2 = p0 + 512 * 8;
      const u16* p3 = p0 + 768 * 8;
#pragma unroll 4
      for (int kb = 0; kb < 32; ++kb) {
        H8 hp = *(const H8*)&hs16[kb * 4];
        g0 = dot8(*(const H8*)p0, hp, g0); p0 += 8192;
        g1 = dot8(*(const H8*)p1, hp, g1); p1 += 8192;
        g2 = dot8(*(const H8*)p2, hp, g2); p2 += 8192;
        g3 = dot8(*(const H8*)p3, hp, g3); p3 += 8192;
      }
    } else {
      const float* W = (const float*)Whh_q;
      const float* p0 = W + (size_t)j * 256;
#pragma unroll 2
      for (int kb = 0; kb < 32; ++kb) {
        H8 hp = *(const H8*)&hs16[kb * 4];
        float hf[8]; unpackH8(hp, hf);
        float w0[8], w1[8], w2[8], w3[8];
        ldf8(p0 + kb * 8, w0);
        ldf8(p0 + 256 * 256 + kb * 8, w1);
        ldf8(p0 + 512 * 256 + kb * 8, w2);
        ldf8(p0 + 768 * 256 + kb * 8, w3);
#pragma unroll
        for (int i = 0; i < 8; ++i) {
          g0 = fmaf(hf[i], w0[i], g0);
          g1 = fmaf(hf[i], w1[i], g1);
          g2 = fmaf(hf[i], w2[i], g2);
          g3 = fmaf(hf[i], w3[i], g3);
        }
      }
    }
  };

  // ---- gates: torch LSTMCell order i,f,g,o; writes h,c f16 to hs16 ----
  auto gates_apply = [&](float g0, float g1, float g2, float g3, float ytil) {
    g0 += ytil * Wih[j]       + bih[j]       + bhh[j];
    g1 += ytil * Wih[j + 256] + bih[j + 256] + bhh[j + 256];
    g2 += ytil * Wih[j + 512] + bih[j + 512] + bhh[j + 512];
    g3 += ytil * Wih[j + 768] + bih[j + 768] + bhh[j + 768];
    float c = sigmoid_fast(g1) * creg + sigmoid_fast(g0) * tanh_fast(g2);
    float h = sigmoid_fast(g3) * tanh_fast(c);
    creg = c;
    u16* hsu = (u16*)hs16;
    hsu[j] = f2h(h);
    hsu[256 + j] = f2h(c);
  };

  // ---- head: ((concat[h,ct] @ Wy^T + b) . vy + b) -> out[idx*B+b], sc[0] ----
  auto head_store = [&](int outIdx) {
    float p = 0.f;
    if (WQ) {
      const u16* W = (const u16*)Wy_q;
      const u16* ph = W + (size_t)j * 8;             // kb 0..31 (h seg)
      const u16* pc = W + (size_t)(32 * 256 + j) * 8; // kb 32..63 (ct seg)
#pragma unroll 4
      for (int kb = 0; kb < 32; ++kb) {
        H8 hp = *(const H8*)&hs16[kb * 4];
        H8 cp = *(const H8*)&ctx16p[kb * 4];
        p = dot8(*(const H8*)ph, hp, p); ph += 2048;
        p = dot8(*(const H8*)pc, cp, p); pc += 2048;
      }
    } else {
      const float* W = (const float*)Wy_q + (size_t)j * 512;
      for (int kb = 0; kb < 32; ++kb) {
        H8 hp = *(const H8*)&hs16[kb * 4];
        float hf[8]; unpackH8(hp, hf);
        float w0[8], w1[8];
        ldf8(W + kb * 8, w0);
        ldf8(W + 256 + kb * 8, w1);
#pragma unroll
        for (int i = 0; i < 8; ++i) {
          p = fmaf(hf[i], w0[i], p);
          p = fmaf(ctx[kb * 8 + i], w1[i], p);
        }
      }
    }
    float pp = (p + Wy_b[j]) * vy_w[j];
#pragma unroll
    for (int off = 32; off; off >>= 1) pp += __shfl_xor(pp, off, 64);
    if ((j & 63) == 0) red[wv] = pp;
    __syncthreads();
    if (j == 0) {
      float o = red[0] + red[1] + red[2] + red[3] + vy_b[0];
      out[(size_t)outIdx * BB + b] = o;
      sc[0] = o;
    }
    __syncthreads();
  };

  // ================= scan over T steps =================
  for (int step = 0; step < TT; ++step) {
    // ---- stream: x1[j] = [h,c].Wd[j] + b ; g0..g3 = Whh@h rows j+256q ----
    float ax0 = 0.f, ax1 = 0.f, g0, g1, g2, g3;
    {
      if (WQ) {
        const u16* Wd16 = (const u16*)Wd_q;
        const u16* Wh16 = (const u16*)Whh_q;
        const u16* pdh = Wd16 + (size_t)j * 8;                // kb 0..31 (h)
        const u16* pdc = Wd16 + (size_t)(32 * 256 + j) * 8;   // kb 32..63 (c)
        const u16* p0 = Wh16 + (size_t)j * 8;
        const u16* p1 = p0 + 256 * 8;
        const u16* p2 = p0 + 512 * 8;
        const u16* p3 = p0 + 768 * 8;
        float b0 = 0.f, b1 = 0.f, b2 = 0.f, b3 = 0.f;
#pragma unroll 4
        for (int kb = 0; kb < 32; ++kb) {
          H8 hp = *(const H8*)&hs16[kb * 4];
          H8 cp = *(const H8*)&hs16[128 + kb * 4];
          ax0 = dot8(*(const H8*)pdh, hp, ax0); pdh += 2048;
          ax1 = dot8(*(const H8*)pdc, cp, ax1); pdc += 2048;
          b0 = dot8(*(const H8*)p0, hp, b0); p0 += 8192;
          b1 = dot8(*(const H8*)p1, hp, b1); p1 += 8192;
          b2 = dot8(*(const H8*)p2, hp, b2); p2 += 8192;
          b3 = dot8(*(const H8*)p3, hp, b3); p3 += 8192;
        }
        g0 = b0; g1 = b1; g2 = b2; g3 = b3;
      } else {
        const float* wd = (const float*)Wd_q + (size_t)j * 512;
        const float* w0p = (const float*)Whh_q + (size_t)j * 256;
        float b0 = 0.f, b1 = 0.f, b2 = 0.f, b3 = 0.f;
#pragma unroll 2
        for (int kb = 0; kb < 32; ++kb) {
          H8 hp = *(const H8*)&hs16[kb * 4];
          H8 cp = *(const H8*)&hs16[128 + kb * 4];
          float hf[8], cf[8]; unpackH8(hp, hf); unpackH8(cp, cf);
          float wh[8], wc[8], w0[8], w1[8], w2[8], w3[8];
          ldf8(wd + kb * 8, wh);
          ldf8(wd + 256 + kb * 8, wc);
          ldf8(w0p + kb * 8, w0);
          ldf8(w0p + 256 * 256 + kb * 8, w1);
          ldf8(w0p + 512 * 256 + kb * 8, w2);
          ldf8(w0p + 768 * 256 + kb * 8, w3);
#pragma unroll
          for (int i = 0; i < 8; ++i) {
            ax0 = fmaf(hf[i], wh[i], ax0);
            ax1 = fmaf(cf[i], wc[i], ax1);
            b0 = fmaf(hf[i], w0[i], b0);
            b1 = fmaf(hf[i], w1[i], b1);
            b2 = fmaf(hf[i], w2[i], b2);
            b3 = fmaf(hf[i], w3[i], b3);
          }
        }
        g0 = b0; g1 = b1; g2 = b2; g3 = b3;
      }
      x1s[j] = ax0 + ax1 + Wd_b[j];
    }
    __syncthreads();

    // ---- B1: l[t] quarter-partials; thread = (q = j>>6, t = j&63) ----
    {
      const int q = wv, tq = j & 63;
      const u16* __restrict__ yrow = &y1l[tq * YS + q * 64];
      const float* __restrict__ xp = &x1s[q * 64];
      const float* __restrict__ vp = vd_w + q * 64;
      float lp = 0.f;
#pragma unroll 2
      for (int m0 = 0; m0 < 64; m0 += 8) {
        H8 yv = *(const H8*)(yrow + m0);
        float yf[8]; unpackH8(yv, yf);
        float xf[8]; ldf8(xp + m0, xf);
        float vf[8]; ldf8(vp + m0, vf);
#pragma unroll
        for (int mm = 0; mm < 8; ++mm) {
          float z = tanh_fast(xf[mm] + yf[mm]);
          lp = fmaf(z, vf[mm], lp);
        }
      }
      lpart[q][tq] = lp;
    }
    __syncthreads();

    // ---- softmax over t (wave 0) -> betas16 (f16) ----
    if (j < 64) {
      const int t = j;
      float l = lpart[0][t] + lpart[1][t] + lpart[2][t] + lpart[3][t];
      float mx = l;
#pragma unroll
      for (int off = 32; off; off >>= 1) mx = fmaxf(mx, __shfl_xor(mx, off, 64));
      float e = __builtin_amdgcn_exp2f((l - mx) * 1.4426950408889634f);
      float sm = e;
#pragma unroll
      for (int off = 32; off; off >>= 1) sm += __shfl_xor(sm, off, 64);
      betas16[t] = f2h(e * __builtin_amdgcn_rcpf(sm));
    }
    __syncthreads();

    // ---- B2: ct[m] = sum_t beta[t]*E[t][m]  (E^T pairs, fdot2) ----
    {
      const u16* __restrict__ ep = &e16T[j * ES];
      float acc = 0.f;
#pragma unroll
      for (int t0 = 0; t0 < TT; t0 += 8) {
        h2 e0 = *(const h2*)(ep + t0);
        h2 e1 = *(const h2*)(ep + t0 + 2);
        h2 e2 = *(const h2*)(ep + t0 + 4);
        h2 e3 = *(const h2*)(ep + t0 + 6);
        H8 bp = *(const H8*)&betas16[t0];
        acc = FDOT2(bp.p[0], e0, acc);
        acc = FDOT2(bp.p[1], e1, acc);
        acc = FDOT2(bp.p[2], e2, acc);
        acc = FDOT2(bp.p[3], e3, acc);
      }
      ctx[j] = acc;
      ((u16*)ctx16p)[j] = f2h(acc);
    }
    // ---- ytil = ct.wt + y_t*wt[M] + wt_b (all threads compute) ----
    {
      float p = ctx[j] * wt_w[j];
#pragma unroll
      for (int off = 32; off; off >>= 1) p += __shfl_xor(p, off, 64);
      if ((j & 63) == 0) red[wv] = p;
    }
    __syncthreads();
    {
      float ytil = red[0] + red[1] + red[2] + red[3]
                 + yin[(size_t)b * TT + step] * wt_w[MM] + wt_b[0];
      gates_apply(g0, g1, g2, g3, ytil);
    }
    __syncthreads();
  }

  // ================= finals =================
  float ctdot;
  {
    float p = ctx[j] * wt_w[j];
#pragma unroll
    for (int off = 32; off; off >>= 1) p += __shfl_xor(p, off, 64);
    if ((j & 63) == 0) red[wv] = p;
    __syncthreads();
    ctdot = red[0] + red[1] + red[2] + red[3];
    __syncthreads();
  }

  head_store(0);  // y_Tp1 (sc[0] holds it for train==0 feedback)

  const int tr = train[0];
  for (int e = 0; e < 2; ++e) {
    float inp = tr ? tar[(size_t)b * 2 + e] : sc[0];
    float ytil = ctdot + inp * wt_w[MM] + wt_b[0];
    float g0, g1, g2, g3;
    mv4(g0, g1, g2, g3);
    gates_apply(g0, g1, g2, g3, ytil);
    __syncthreads();
    head_store(1 + e);
  }
}

extern "C" void kernel_launch(void* const* d_in, const int* in_sizes, int n_in,
                              void* d_out, int out_size, void* d_ws, size_t ws_size,
                              hipStream_t stream) {
  const float* E     = (const float*)d_in[0];
  const float* yin   = (const float*)d_in[1];
  const float* tar   = (const float*)d_in[2];
  const int*   train = (const int*)d_in[3];
  const float* Wd_w  = (const float*)d_in[4];
  const float* Wd_b  = (const float*)d_in[5];
  const float* Ud_w  = (const float*)d_in[6];
  const float* vd_w  = (const float*)d_in[7];
  const float* wt_w  = (const float*)d_in[8];
  const float* wt_b  = (const float*)d_in[9];
  const float* Wy_w  = (const float*)d_in[10];
  const float* Wy_b  = (const float*)d_in[11];
  const float* vy_w  = (const float*)d_in[12];
  const float* vy_b  = (const float*)d_in[13];
  const float* Wih   = (const float*)d_in[14];
  const float* Whh   = (const float*)d_in[15];
  const float* bih   = (const float*)d_in[16];
  const float* bhh   = (const float*)d_in[17];

  float* out = (float*)d_out;

  if (ws_size >= (size_t)WQ_BYTES) {
    u16* wq = (u16*)d_ws;
    prep_kernel<<<dim3(WQ_ELEMS / 256), dim3(256), 0, stream>>>(
        Wd_w, Whh, Wy_w, wq);
    scan_kernel<1><<<dim3(BB), dim3(256), 0, stream>>>(
        E, yin, tar, train, wq + WD16_OFF, Wd_b, Ud_w, vd_w, wt_w, wt_b,
        wq + WY16_OFF, Wy_b, vy_w, vy_b, Wih, wq + WHH16_OFF, bih, bhh, out);
  } else {
    scan_kernel<0><<<dim3(BB), dim3(256), 0, stream>>>(
        E, yin, tar, train, Wd_w, Wd_b, Ud_w, vd_w, wt_w, wt_b,
        Wy_w, Wy_b, vy_w, vy_b, Wih, Whh, bih, bhh, out);
  }

  (void)in_sizes; (void)n_in; (void)out_size;
}